// Round 1
// baseline (398.614 us; speedup 1.0000x reference)
//
#include <hip/hip_runtime.h>

// MultiBoxLoss_four_corners — B=64, P=8732, C=81, NEG_POS_RATIO=3
// Outputs: (loss_l/N, loss_c/N, loss_four_corners/N)  -> d_out[0..2] (f32)

#define NB 64
#define NP 8732
#define NC 81
constexpr int BP = NB * NP;          // 558848, exactly divisible by 256

__device__ inline float sl1(float d) {
    d = fabsf(d);
    return d < 1.0f ? 0.5f * d * d : d - 0.5f;
}

// block = 256 threads = 4 waves. Returns total to ALL threads.
__device__ inline float block_reduce_f(float v, float* sred) {
    #pragma unroll
    for (int o = 32; o; o >>= 1) v += __shfl_xor(v, o, 64);
    const int wave = threadIdx.x >> 6;
    const int lane = threadIdx.x & 63;
    __syncthreads();                 // protect sred against previous use
    if (lane == 0) sred[wave] = v;
    __syncthreads();
    return sred[0] + sred[1] + sred[2] + sred[3];
}

__device__ inline int block_reduce_i(int v, int* sred) {
    #pragma unroll
    for (int o = 32; o; o >>= 1) v += __shfl_xor(v, o, 64);
    const int wave = threadIdx.x >> 6;
    const int lane = threadIdx.x & 63;
    __syncthreads();
    if (lane == 0) sred[wave] = v;
    __syncthreads();
    return sred[0] + sred[1] + sred[2] + sred[3];
}

__global__ void k_init(float* acc) {
    if (threadIdx.x < 2) acc[threadIdx.x] = 0.0f;
}

// One prior per thread for loc/fc smooth-L1; one prior per wave-iteration for CE.
__global__ __launch_bounds__(256) void k_main(
    const float* __restrict__ loc_data, const float* __restrict__ conf_data,
    const float* __restrict__ fc_data,  const float* __restrict__ loc_t,
    const float* __restrict__ fc_t,     const int* __restrict__ conf_t,
    float* __restrict__ ce, float* __restrict__ acc)
{
    __shared__ float lds_ce[256];
    __shared__ float sred[4];
    const int t    = threadIdx.x;
    const int lane = t & 63;
    const int wave = t >> 6;
    const int pStart = blockIdx.x << 8;
    const int g = pStart + t;

    // ---- smooth-L1 on loc (4) and four_corners (8), masked by pos ----
    const float posf = (conf_t[g] > 0) ? 1.0f : 0.0f;
    float4 a  = ((const float4*)loc_data)[g];
    float4 at = ((const float4*)loc_t)[g];
    float l_sum = (sl1(a.x - at.x) + sl1(a.y - at.y) +
                   sl1(a.z - at.z) + sl1(a.w - at.w)) * posf;
    float4 c0 = ((const float4*)fc_data)[2 * g];
    float4 c1 = ((const float4*)fc_data)[2 * g + 1];
    float4 d0 = ((const float4*)fc_t)[2 * g];
    float4 d1 = ((const float4*)fc_t)[2 * g + 1];
    float f_sum = (sl1(c0.x - d0.x) + sl1(c0.y - d0.y) + sl1(c0.z - d0.z) + sl1(c0.w - d0.w) +
                   sl1(c1.x - d1.x) + sl1(c1.y - d1.y) + sl1(c1.z - d1.z) + sl1(c1.w - d1.w)) * posf;

    // ---- CE: logsumexp(conf_row) - conf_row[tgt], one prior per wave iter ----
    const int base = pStart + (wave << 6);
    for (int i = 0; i < 64; ++i) {
        const size_t off = (size_t)(base + i) * NC;
        float x0 = conf_data[off + lane];                                   // 64 coalesced
        float x1 = (lane < NC - 64) ? conf_data[off + 64 + lane] : -87.0f;  // 17 tail
        float s = __expf(x0) + __expf(x1);
        #pragma unroll
        for (int o = 32; o; o >>= 1) s += __shfl_xor(s, o, 64);
        int tgt = conf_t[base + i];                                          // uniform
        float gx = (tgt < 64) ? __shfl(x0, tgt, 64) : __shfl(x1, tgt - 64, 64);
        if (lane == 0) lds_ce[(wave << 6) + i] = __logf(s) - gx;
    }

    float lt = block_reduce_f(l_sum, sred);
    float ft = block_reduce_f(f_sum, sred);
    if (t == 0) {
        atomicAdd(&acc[0], lt);
        atomicAdd(&acc[1], ft);
    }
    __syncthreads();
    ce[g] = lds_ce[t];               // coalesced CE writeback
}

// One block per batch: npos, pos/neg CE sums, hard-negative mining.
__global__ __launch_bounds__(256) void k_batch(
    const float* __restrict__ ce, const int* __restrict__ conf_t,
    float* __restrict__ loss_c_b, int* __restrict__ npos_b)
{
    __shared__ float ce_s[NP];       // ~35 KB: negative CE, positives = -1
    __shared__ float sredf[4];
    __shared__ int   sredi[4];
    const int b = blockIdx.x;
    const int t = threadIdx.x;
    const float* crow = ce + (size_t)b * NP;
    const int*   trow = conf_t + (size_t)b * NP;

    int   np_t = 0;
    float sp_t = 0.0f, sn_t = 0.0f;
    for (int p = t; p < NP; p += 256) {
        float v = crow[p];
        if (trow[p] > 0) { np_t++; sp_t += v; ce_s[p] = -1.0f; }
        else             { sn_t += v;         ce_s[p] = v;     }
    }
    int   npos = block_reduce_i(np_t, sredi);
    float spos = block_reduce_f(sp_t, sredf);
    float sneg = block_reduce_f(sn_t, sredf);  // syncs also cover ce_s writes

    const int nneg    = NP - npos;
    const int num_neg = min(3 * npos, NP - 1);
    float loss_c;
    if (num_neg >= nneg) {
        // all negatives selected (always true for this data distribution)
        loss_c = spos + sneg;
    } else if (num_neg <= 0) {
        loss_c = spos;
    } else {
        // general path: sum of top-K negative CE values.
        // Binary search K-th largest over nonneg-float bit patterns (monotone).
        const int K = num_neg;
        unsigned lo = 0u, hi = 0x7f800000u;
        while (lo < hi) {
            unsigned mid = lo + ((hi - lo) >> 1);
            float v = __uint_as_float(mid);
            int c_t = 0;
            for (int p = t; p < NP; p += 256) c_t += (ce_s[p] > v) ? 1 : 0;
            int cnt = block_reduce_i(c_t, sredi);
            if (cnt < K) hi = mid; else lo = mid + 1;
        }
        float v = __uint_as_float(lo);   // K-th largest value
        int c_t = 0; float s_t = 0.0f;
        for (int p = t; p < NP; p += 256) {
            float x = ce_s[p];
            if (x > v) { c_t++; s_t += x; }
        }
        int   cnt = block_reduce_i(c_t, sredi);
        float sgt = block_reduce_f(s_t, sredf);
        loss_c = spos + sgt + (float)(K - cnt) * v;  // ties all equal v
    }
    if (t == 0) { loss_c_b[b] = loss_c; npos_b[b] = npos; }
}

__global__ void k_final(const float* __restrict__ acc,
                        const float* __restrict__ loss_c_b,
                        const int* __restrict__ npos_b,
                        float* __restrict__ out)
{
    const int t = threadIdx.x;       // 64 threads
    float lc = loss_c_b[t];
    int   np = npos_b[t];
    #pragma unroll
    for (int o = 32; o; o >>= 1) {
        lc += __shfl_xor(lc, o, 64);
        np += __shfl_xor(np, o, 64);
    }
    if (t == 0) {
        float N = (float)np;
        out[0] = acc[0] / N;
        out[1] = lc / N;
        out[2] = acc[1] / N;
    }
}

extern "C" void kernel_launch(void* const* d_in, const int* in_sizes, int n_in,
                              void* d_out, int out_size, void* d_ws, size_t ws_size,
                              hipStream_t stream)
{
    const float* loc_data  = (const float*)d_in[0];
    const float* conf_data = (const float*)d_in[1];
    const float* fc_data   = (const float*)d_in[2];
    const float* loc_t     = (const float*)d_in[3];
    const float* fc_t      = (const float*)d_in[4];
    const int*   conf_t    = (const int*)d_in[5];
    float* out = (float*)d_out;

    // workspace: ce[BP] | acc[2] (loss_l, loss_fc) | loss_c_b[64] | npos_b[64]
    float* ce       = (float*)d_ws;
    float* acc      = ce + BP;
    float* loss_c_b = acc + 2;
    int*   npos_b   = (int*)(loss_c_b + 64);

    hipLaunchKernelGGL(k_init,  dim3(1),        dim3(64),  0, stream, acc);
    hipLaunchKernelGGL(k_main,  dim3(BP / 256), dim3(256), 0, stream,
                       loc_data, conf_data, fc_data, loc_t, fc_t, conf_t, ce, acc);
    hipLaunchKernelGGL(k_batch, dim3(NB),       dim3(256), 0, stream,
                       ce, conf_t, loss_c_b, npos_b);
    hipLaunchKernelGGL(k_final, dim3(1),        dim3(64),  0, stream,
                       acc, loss_c_b, npos_b, out);
}

// Round 2
// 315.391 us; speedup vs baseline: 1.2639x; 1.2639x over previous
//
#include <hip/hip_runtime.h>

// MultiBoxLoss_four_corners — B=64, P=8732, C=81, NEG_POS_RATIO=3
// Outputs: (loss_l/N, loss_c/N, loss_four_corners/N) -> d_out[0..2] (f32)
//
// R2: one-prior-per-thread CE (no shuffle serialization), per-batch sums via
// atomics in k_main so k_batch's common path is O(1). General top-K mining
// path retained (binary search over float bits) but only runs when needed.

#define NB 64
#define NP 8732
#define NC 81
constexpr int BP = NB * NP;              // 558848
constexpr int PBLK = (NP + 255) / 256;   // 35 blocks per batch (tail 28)

__device__ inline float sl1(float d) {
    d = fabsf(d);
    return d < 1.0f ? 0.5f * d * d : d - 0.5f;
}

// ws layout: ce[BP] | acc[2] | npos_b[64](int) | spos_b[64] | sneg_b[64] | loss_c_b[64]
__global__ void k_init(float* acc_area) {
    // zero acc[2] + npos_b + spos_b + sneg_b  (2 + 192 words)
    if (threadIdx.x < 194) acc_area[threadIdx.x] = 0.0f;
}

__global__ __launch_bounds__(256) void k_main(
    const float* __restrict__ loc_data, const float* __restrict__ conf_data,
    const float* __restrict__ fc_data,  const float* __restrict__ loc_t,
    const float* __restrict__ fc_t,     const int* __restrict__ conf_t,
    float* __restrict__ ce, float* __restrict__ acc,
    int* __restrict__ npos_b, float* __restrict__ spos_b, float* __restrict__ sneg_b)
{
    const int b = blockIdx.y;
    const int t = threadIdx.x;
    const int p = (blockIdx.x << 8) + t;

    float l_sum = 0.0f, f_sum = 0.0f, sp = 0.0f, sn = 0.0f;
    int np = 0;

    if (p < NP) {
        const size_t g = (size_t)b * NP + p;
        const int tgt = conf_t[g];
        const float posf = (tgt > 0) ? 1.0f : 0.0f;
        np = (tgt > 0) ? 1 : 0;

        // smooth-L1 on loc (4) and four_corners (8); float4-aligned
        float4 a  = ((const float4*)loc_data)[g];
        float4 at = ((const float4*)loc_t)[g];
        l_sum = (sl1(a.x - at.x) + sl1(a.y - at.y) +
                 sl1(a.z - at.z) + sl1(a.w - at.w)) * posf;
        float4 c0 = ((const float4*)fc_data)[2 * g];
        float4 c1 = ((const float4*)fc_data)[2 * g + 1];
        float4 d0 = ((const float4*)fc_t)[2 * g];
        float4 d1 = ((const float4*)fc_t)[2 * g + 1];
        f_sum = (sl1(c0.x - d0.x) + sl1(c0.y - d0.y) + sl1(c0.z - d0.z) + sl1(c0.w - d0.w) +
                 sl1(c1.x - d1.x) + sl1(c1.y - d1.y) + sl1(c1.z - d1.z) + sl1(c1.w - d1.w)) * posf;

        // CE: this thread streams its own 81-float row (4-B aligned only -> scalar)
        const float* row = conf_data + g * NC;
        float s0 = 0.0f, s1 = 0.0f, s2 = 0.0f, s3 = 0.0f;
        #pragma unroll 5
        for (int c = 0; c < 80; c += 4) {
            s0 += __expf(row[c]);
            s1 += __expf(row[c + 1]);
            s2 += __expf(row[c + 2]);
            s3 += __expf(row[c + 3]);
        }
        float s = (s0 + s1) + (s2 + s3) + __expf(row[80]);
        float cev = __logf(s) - row[tgt];
        ce[g] = cev;
        sp = cev * posf;
        sn = cev - sp;           // cev * (1-posf)
    }

    // block reduce 5 values -> atomics
    __shared__ float red[4][5];
    const int wave = t >> 6, lane = t & 63;
    float vnp = (float)np;
    #pragma unroll
    for (int o = 32; o; o >>= 1) {
        l_sum += __shfl_xor(l_sum, o, 64);
        f_sum += __shfl_xor(f_sum, o, 64);
        sp    += __shfl_xor(sp, o, 64);
        sn    += __shfl_xor(sn, o, 64);
        vnp   += __shfl_xor(vnp, o, 64);
    }
    if (lane == 0) {
        red[wave][0] = l_sum; red[wave][1] = f_sum;
        red[wave][2] = sp;    red[wave][3] = sn;   red[wave][4] = vnp;
    }
    __syncthreads();
    if (t == 0) {
        float rl = 0, rf = 0, rp = 0, rn = 0, rc = 0;
        #pragma unroll
        for (int w = 0; w < 4; ++w) {
            rl += red[w][0]; rf += red[w][1]; rp += red[w][2];
            rn += red[w][3]; rc += red[w][4];
        }
        atomicAdd(&acc[0], rl);
        atomicAdd(&acc[1], rf);
        atomicAdd(&spos_b[b], rp);
        atomicAdd(&sneg_b[b], rn);
        atomicAdd(&npos_b[b], (int)rc);
    }
}

// One block per batch. Common path: O(1). Rare path: top-K via bit binary search.
__global__ __launch_bounds__(256) void k_batch(
    const float* __restrict__ ce, const int* __restrict__ conf_t,
    const int* __restrict__ npos_b, const float* __restrict__ spos_b,
    const float* __restrict__ sneg_b, float* __restrict__ loss_c_b)
{
    const int b = blockIdx.x;
    const int t = threadIdx.x;
    const int npos    = npos_b[b];
    const int nneg    = NP - npos;
    const int num_neg = min(3 * npos, NP - 1);

    if (num_neg >= nneg) {              // all negatives selected (this dataset)
        if (t == 0) loss_c_b[b] = spos_b[b] + sneg_b[b];
        return;
    }
    if (num_neg <= 0) {
        if (t == 0) loss_c_b[b] = spos_b[b];
        return;
    }

    // general path: stage negative CE into LDS (positives -> -1), top-K sum
    __shared__ float ce_s[NP];
    __shared__ float sredf[4];
    __shared__ int   sredi[4];
    const float* crow = ce + (size_t)b * NP;
    const int*   trow = conf_t + (size_t)b * NP;
    for (int p = t; p < NP; p += 256)
        ce_s[p] = (trow[p] > 0) ? -1.0f : crow[p];
    __syncthreads();

    const int wave = t >> 6, lane = t & 63;
    const int K = num_neg;
    unsigned lo = 0u, hi = 0x7f800000u;
    while (lo < hi) {
        unsigned mid = lo + ((hi - lo) >> 1);
        float v = __uint_as_float(mid);
        int c_t = 0;
        for (int p = t; p < NP; p += 256) c_t += (ce_s[p] > v) ? 1 : 0;
        #pragma unroll
        for (int o = 32; o; o >>= 1) c_t += __shfl_xor(c_t, o, 64);
        __syncthreads();
        if (lane == 0) sredi[wave] = c_t;
        __syncthreads();
        int cnt = sredi[0] + sredi[1] + sredi[2] + sredi[3];
        if (cnt < K) hi = mid; else lo = mid + 1;
    }
    float v = __uint_as_float(lo);       // K-th largest negative CE
    int c_t = 0; float s_t = 0.0f;
    for (int p = t; p < NP; p += 256) {
        float x = ce_s[p];
        if (x > v) { c_t++; s_t += x; }
    }
    #pragma unroll
    for (int o = 32; o; o >>= 1) {
        c_t += __shfl_xor(c_t, o, 64);
        s_t += __shfl_xor(s_t, o, 64);
    }
    __syncthreads();
    if (lane == 0) { sredi[wave] = c_t; sredf[wave] = s_t; }
    __syncthreads();
    if (t == 0) {
        int   cnt = sredi[0] + sredi[1] + sredi[2] + sredi[3];
        float sgt = sredf[0] + sredf[1] + sredf[2] + sredf[3];
        loss_c_b[b] = spos_b[b] + sgt + (float)(K - cnt) * v;
    }
}

__global__ void k_final(const float* __restrict__ acc,
                        const float* __restrict__ loss_c_b,
                        const int* __restrict__ npos_b,
                        float* __restrict__ out)
{
    const int t = threadIdx.x;           // 64 threads
    float lc = loss_c_b[t];
    int   np = npos_b[t];
    #pragma unroll
    for (int o = 32; o; o >>= 1) {
        lc += __shfl_xor(lc, o, 64);
        np += __shfl_xor(np, o, 64);
    }
    if (t == 0) {
        float N = (float)np;
        out[0] = acc[0] / N;
        out[1] = lc / N;
        out[2] = acc[1] / N;
    }
}

extern "C" void kernel_launch(void* const* d_in, const int* in_sizes, int n_in,
                              void* d_out, int out_size, void* d_ws, size_t ws_size,
                              hipStream_t stream)
{
    const float* loc_data  = (const float*)d_in[0];
    const float* conf_data = (const float*)d_in[1];
    const float* fc_data   = (const float*)d_in[2];
    const float* loc_t     = (const float*)d_in[3];
    const float* fc_t      = (const float*)d_in[4];
    const int*   conf_t    = (const int*)d_in[5];
    float* out = (float*)d_out;

    float* ce       = (float*)d_ws;
    float* acc      = ce + BP;           // [2]
    int*   npos_b   = (int*)(acc + 2);   // [64]
    float* spos_b   = (float*)(npos_b + 64);
    float* sneg_b   = spos_b + 64;
    float* loss_c_b = sneg_b + 64;

    hipLaunchKernelGGL(k_init,  dim3(1), dim3(256), 0, stream, acc);
    hipLaunchKernelGGL(k_main,  dim3(PBLK, NB), dim3(256), 0, stream,
                       loc_data, conf_data, fc_data, loc_t, fc_t, conf_t,
                       ce, acc, npos_b, spos_b, sneg_b);
    hipLaunchKernelGGL(k_batch, dim3(NB), dim3(256), 0, stream,
                       ce, conf_t, npos_b, spos_b, sneg_b, loss_c_b);
    hipLaunchKernelGGL(k_final, dim3(1), dim3(64), 0, stream,
                       acc, loss_c_b, npos_b, out);
}